// Round 1
// baseline (302.896 us; speedup 1.0000x reference)
//
#include <hip/hip_runtime.h>
#include <math.h>

// Problem constants (from setup_inputs): B=8, S=8192, D=1024, 64 hidden units.
#define BATCH 8
#define SEQ   8192
#define DIM   1024

// out[b,d] = iw[A-1,d] * sum_a w[a] * hs[b, idx[a], d]
// Only spine values {0,1,2,5} can qualify (pc keys need position<=12, sp<position),
// and the qualifying set is always a PREFIX of {0,1,2,5}. So:
//  - speculatively load all 4 candidate hs rows + all 4 possible iw rows at kernel
//    top (addresses are position-independent) so HBM latency overlaps the MLP;
//  - each wave computes the 64-unit MLP redundantly (lane = tid&63) -> weights are
//    wave-uniform after broadcast; no LDS, no __syncthreads on the critical path.
__global__ __launch_bounds__(256) void flfa_kernel(
    const float* __restrict__ hs,   // (B, SEQ, DIM)
    const float* __restrict__ iw,   // (10, DIM)
    const float* __restrict__ w1,   // (64,1) -> w1[j]
    const float* __restrict__ b1,   // (64,)
    const float* __restrict__ w2,   // (1,64) -> w2[j]
    const float* __restrict__ b2,   // (1,)
    const int* __restrict__ posp,   // scalar position
    float* __restrict__ out)        // (B, DIM)
{
    const int tid  = threadIdx.x;
    const int lane = tid & 63;
    const int b    = blockIdx.x;
    const int d    = tid * 4;

    // ---- speculative loads: issue everything up front (position-independent) ----
    const float* hb = hs + (size_t)b * SEQ * DIM + d;
    const float4 h0 = *(const float4*)(hb + 0 * DIM);   // spine 0
    const float4 h1 = *(const float4*)(hb + 1 * DIM);   // spine 1
    const float4 h2 = *(const float4*)(hb + 2 * DIM);   // spine 2
    const float4 h3 = *(const float4*)(hb + 5 * DIM);   // spine 5
    const float4 r0 = *(const float4*)(iw + 0 * DIM + d);  // iw row for A=1
    const float4 r1 = *(const float4*)(iw + 1 * DIM + d);  // A=2
    const float4 r2 = *(const float4*)(iw + 2 * DIM + d);  // A=3
    const float4 r3 = *(const float4*)(iw + 3 * DIM + d);  // A=4

    // MLP params: lane j owns hidden unit j (identical across the 4 waves).
    const float w1j = w1[lane];
    const float b1j = b1[lane];
    const float w2j = w2[lane];
    const float b2v = b2[0];

    const int position = *posp;
    // A = |{sp in {0,1,2,5} : sp < position}| when 1 <= position <= 12, else 0.
    int A = 0;
    if (position >= 1 && position <= 12)
        A = (position > 0) + (position > 1) + (position > 2) + (position > 5);

    // ---- per-wave MLP (redundant across waves; overlaps load latency) ----
    const int spine_vals[4] = {0, 1, 2, 5};
    float wv[4];
    float wsum = 0.0f;
    #pragma unroll
    for (int a = 0; a < 4; ++a) {
        // path count c = t_k, k = position - sp; t1=1, t2=2, t_k = t_{k-1}+t_{k-2}
        const int k = position - spine_vals[a];
        float c = 0.0f;
        if (k == 1)      c = 1.0f;
        else if (k == 2) c = 2.0f;
        else if (k >= 3) {
            float ta = 1.0f, tb = 2.0f;
            for (int q = 3; q <= k; ++q) { float t = ta + tb; ta = tb; tb = t; }
            c = tb;
        }
        // hidden unit j: relu(c*w1[j]+b1[j]) * w2[j], reduce over 64 lanes
        float h = fmaxf(fmaf(c, w1j, b1j), 0.0f) * w2j;
        #pragma unroll
        for (int off = 32; off > 0; off >>= 1)
            h += __shfl_down(h, off, 64);
        const float z  = __shfl(h, 0, 64) + b2v;       // broadcast: wave-uniform
        // numerically-stable softplus: max(z,0) + log1p(exp(-|z|))
        const float sp = fmaxf(z, 0.0f) + log1pf(expf(-fabsf(z)));
        const float v  = (a < A) ? sp : 0.0f;          // mask excluded anchors
        wv[a] = v;
        wsum += v;
    }
    const float inv = (A > 0) ? 1.0f / wsum : 0.0f;    // zeros output when A==0
    const float wa0 = wv[0] * inv;
    const float wa1 = wv[1] * inv;
    const float wa2 = wv[2] * inv;
    const float wa3 = wv[3] * inv;

    // uniform select of iw row A-1 (static indexing only — no scratch)
    const float4 iw4 = (A <= 1) ? r0 : (A == 2) ? r1 : (A == 3) ? r2 : r3;

    float4 o;
    o.x = (wa0 * h0.x + wa1 * h1.x + wa2 * h2.x + wa3 * h3.x) * iw4.x;
    o.y = (wa0 * h0.y + wa1 * h1.y + wa2 * h2.y + wa3 * h3.y) * iw4.y;
    o.z = (wa0 * h0.z + wa1 * h1.z + wa2 * h2.z + wa3 * h3.z) * iw4.z;
    o.w = (wa0 * h0.w + wa1 * h1.w + wa2 * h2.w + wa3 * h3.w) * iw4.w;
    *(float4*)(out + (size_t)b * DIM + d) = o;
}

extern "C" void kernel_launch(void* const* d_in, const int* in_sizes, int n_in,
                              void* d_out, int out_size, void* d_ws, size_t ws_size,
                              hipStream_t stream) {
    const float* hs  = (const float*)d_in[0];
    const float* iw  = (const float*)d_in[1];
    const float* w1  = (const float*)d_in[2];
    const float* b1  = (const float*)d_in[3];
    const float* w2  = (const float*)d_in[4];
    const float* b2  = (const float*)d_in[5];
    const int*   pos = (const int*)d_in[6];
    float* out = (float*)d_out;

    flfa_kernel<<<dim3(BATCH), dim3(256), 0, stream>>>(hs, iw, w1, b1, w2, b2, pos, out);
}